// Round 1
// baseline (739.676 us; speedup 1.0000x reference)
//
#include <hip/hip_runtime.h>
#include <cstdint>
#include <cstddef>

#define N_NODES 100000
#define N_EDGES 1600000

// ---------------- CSR build ----------------

__global__ void count_edges(const int* __restrict__ dst, int* __restrict__ cnt, int E) {
    int e = blockIdx.x * blockDim.x + threadIdx.x;
    if (e < E) atomicAdd(&cnt[dst[e]], 1);
}

// Exclusive scan, 1024 elements per block (256 threads x 4).
// Writes per-block totals to blockSums (if non-null).
__global__ void scan_phase1(const int* __restrict__ in, int* __restrict__ out,
                            int* __restrict__ blockSums, int n) {
    __shared__ int sdata[256];
    int base = blockIdx.x * 1024 + threadIdx.x * 4;
    int v0 = 0, v1 = 0, v2 = 0, v3 = 0;
    if (base + 0 < n) v0 = in[base + 0];
    if (base + 1 < n) v1 = in[base + 1];
    if (base + 2 < n) v2 = in[base + 2];
    if (base + 3 < n) v3 = in[base + 3];
    int s = v0 + v1 + v2 + v3;
    sdata[threadIdx.x] = s;
    __syncthreads();
    int acc = s;
    for (int off = 1; off < 256; off <<= 1) {
        int t = (threadIdx.x >= off) ? sdata[threadIdx.x - off] : 0;
        __syncthreads();
        acc += t;
        sdata[threadIdx.x] = acc;
        __syncthreads();
    }
    int excl = acc - s;
    if (base + 0 < n) out[base + 0] = excl;
    if (base + 1 < n) out[base + 1] = excl + v0;
    if (base + 2 < n) out[base + 2] = excl + v0 + v1;
    if (base + 3 < n) out[base + 3] = excl + v0 + v1 + v2;
    if (threadIdx.x == 255 && blockSums) blockSums[blockIdx.x] = acc;
}

__global__ void scan_add(int* __restrict__ offs, const int* __restrict__ blockOffs, int n) {
    int i = blockIdx.x * blockDim.x + threadIdx.x;
    if (i < n) offs[i] += blockOffs[i >> 10];
}

__global__ void fill_csr(const int* __restrict__ src, const int* __restrict__ dst,
                         const int* __restrict__ offs, int* __restrict__ cursor,
                         int* __restrict__ csr, int E) {
    int e = blockIdx.x * blockDim.x + threadIdx.x;
    if (e < E) {
        int d = dst[e];
        int p = atomicAdd(&cursor[d], 1);
        csr[offs[d] + p] = src[e];
    }
}

// ---------------- mean aggregation: one wave per node ----------------

__global__ void aggregate_mean(const float* __restrict__ F, const int* __restrict__ offs,
                               const int* __restrict__ cnt, const int* __restrict__ csr,
                               float* __restrict__ out, int n) {
    int w = (blockIdx.x * blockDim.x + threadIdx.x) >> 6;
    int lane = threadIdx.x & 63;
    if (w >= n) return;
    int beg = offs[w];
    int c = cnt[w];
    float ax = 0.f, ay = 0.f;
    for (int j = 0; j < c; ++j) {
        int s = csr[beg + j];
        float2 v = *reinterpret_cast<const float2*>(F + (size_t)s * 128 + lane * 2);
        ax += v.x;
        ay += v.y;
    }
    float inv = 1.0f / fmaxf((float)c, 1.0f);
    float2 r;
    r.x = ax * inv;
    r.y = ay * inv;
    *reinterpret_cast<float2*>(out + (size_t)w * 128 + lane * 2) = r;
}

// ---------------- fused fp32 tiled GEMM ----------------
// C[r][c] = A1[r][:]@W1[:][c] (+ A2[r][:]@W2[:][c]) + bias[c]  (+relu)
// BM = 128 rows/block, BN = TN*16 cols, K = 128 per segment, staged 8-deep.

template <int TN, bool HAS_A2, bool RELU>
__global__ __launch_bounds__(256) void gemm_tile(const float* __restrict__ A1,
                                                 const float* __restrict__ W1,
                                                 const float* __restrict__ A2,
                                                 const float* __restrict__ W2,
                                                 const float* __restrict__ bias,
                                                 float* __restrict__ C, int n) {
    constexpr int BN = TN * 16;
    constexpr int TM = 8;
    __shared__ float As[8 * 128];   // As[kk][r]  (transposed)
    __shared__ float Bs[8 * BN];    // Bs[kk][c]
    int tid = threadIdx.x;
    int tx = tid & 15, ty = tid >> 4;
    int r0 = ty * TM, c0 = tx * TN;
    int row0 = blockIdx.x * 128;

    float acc[TM][TN];
#pragma unroll
    for (int i = 0; i < TM; i++)
#pragma unroll
        for (int j = 0; j < TN; j++) acc[i][j] = 0.f;

    const float* Ap[2] = {A1, A2};
    const float* Wp[2] = {W1, W2};
    const int nseg = HAS_A2 ? 2 : 1;

    for (int seg = 0; seg < nseg; ++seg) {
        const float* A = Ap[seg];
        const float* W = Wp[seg];
        for (int k0 = 0; k0 < 128; k0 += 8) {
            __syncthreads();
            // A tile: 128 rows x 8 k, transpose into As[kk][r]
            {
                int r = tid >> 1;
                int kg = (tid & 1) * 4;
                int grow = row0 + r;
                float4 v = make_float4(0.f, 0.f, 0.f, 0.f);
                if (grow < n)
                    v = *reinterpret_cast<const float4*>(A + (size_t)grow * 128 + k0 + kg);
                As[(kg + 0) * 128 + r] = v.x;
                As[(kg + 1) * 128 + r] = v.y;
                As[(kg + 2) * 128 + r] = v.z;
                As[(kg + 3) * 128 + r] = v.w;
            }
            // B tile: Bs[kk][c]
            if constexpr (BN == 128) {
                int kk = tid >> 5;
                int c = (tid & 31) * 4;
                *reinterpret_cast<float4*>(&Bs[kk * BN + c]) =
                    *reinterpret_cast<const float4*>(W + (size_t)(k0 + kk) * BN + c);
            } else {
                int kk = tid >> 5;
                int c = (tid & 31) * 2;
                *reinterpret_cast<float2*>(&Bs[kk * BN + c]) =
                    *reinterpret_cast<const float2*>(W + (size_t)(k0 + kk) * BN + c);
            }
            __syncthreads();
#pragma unroll
            for (int kk = 0; kk < 8; ++kk) {
                float a[TM], b[TN];
#pragma unroll
                for (int i = 0; i < TM; i++) a[i] = As[kk * 128 + r0 + i];
#pragma unroll
                for (int j = 0; j < TN; j++) b[j] = Bs[kk * BN + c0 + j];
#pragma unroll
                for (int i = 0; i < TM; i++)
#pragma unroll
                    for (int j = 0; j < TN; j++) acc[i][j] += a[i] * b[j];
            }
        }
    }

    float bv[TN];
#pragma unroll
    for (int j = 0; j < TN; j++) bv[j] = bias ? bias[c0 + j] : 0.f;
#pragma unroll
    for (int i = 0; i < TM; i++) {
        int grow = row0 + r0 + i;
        if (grow < n) {
#pragma unroll
            for (int j = 0; j < TN; j++) {
                float v = acc[i][j] + bv[j];
                if (RELU) v = fmaxf(v, 0.f);
                C[(size_t)grow * BN + c0 + j] = v;
            }
        }
    }
}

// ---------------- in-place row L2 normalize ----------------

__global__ void normalize_rows(float* __restrict__ emb, int n) {
    int w = (blockIdx.x * blockDim.x + threadIdx.x) >> 6;
    int lane = threadIdx.x & 63;
    if (w >= n) return;
    float2 v = *reinterpret_cast<float2*>(emb + (size_t)w * 128 + lane * 2);
    float ss = v.x * v.x + v.y * v.y;
    for (int off = 1; off < 64; off <<= 1) ss += __shfl_xor(ss, off);
    float norm = sqrtf(ss);
    float inv = 1.0f / fmaxf(norm, 1e-12f);
    v.x *= inv;
    v.y *= inv;
    *reinterpret_cast<float2*>(emb + (size_t)w * 128 + lane * 2) = v;
}

// ---------------- launch ----------------

extern "C" void kernel_launch(void* const* d_in, const int* in_sizes, int n_in,
                              void* d_out, int out_size, void* d_ws, size_t ws_size,
                              hipStream_t stream) {
    const float* x   = (const float*)d_in[0];
    const int*   ei  = (const int*)d_in[1];
    const float* W1l = (const float*)d_in[2];
    const float* b1  = (const float*)d_in[3];
    const float* W1r = (const float*)d_in[4];
    const float* W2l = (const float*)d_in[5];
    const float* b2  = (const float*)d_in[6];
    const float* W2r = (const float*)d_in[7];
    const float* Wm  = (const float*)d_in[8];
    const float* bm  = (const float*)d_in[9];

    const int N = N_NODES, E = N_EDGES;
    const int* src = ei;
    const int* dst = ei + E;

    char* ws = (char*)d_ws;
    int* cnt    = (int*)ws;  ws += sizeof(int) * N;
    int* offs   = (int*)ws;  ws += sizeof(int) * N;
    int* cursor = (int*)ws;  ws += sizeof(int) * N;
    int* csr    = (int*)ws;  ws += sizeof(int) * E;
    int* bsums  = (int*)ws;  ws += sizeof(int) * 128;
    int* boffs  = (int*)ws;  ws += sizeof(int) * 128;
    int* bdummy = (int*)ws;  ws += sizeof(int) * 4;
    uintptr_t p = (uintptr_t)ws;
    p = (p + 255) & ~(uintptr_t)255;
    float* mean = (float*)p;
    float* h    = mean + (size_t)N * 128;

    float* outp = (float*)d_out;            // N x 64
    float* emb  = outp + (size_t)N * 64;    // N x 128 (raw emb, normalized in place at the end)

    hipMemsetAsync(cnt, 0, sizeof(int) * N, stream);
    hipMemsetAsync(cursor, 0, sizeof(int) * N, stream);
    count_edges<<<(E + 255) / 256, 256, 0, stream>>>(dst, cnt, E);
    int nblk = (N + 1023) / 1024;  // 98
    scan_phase1<<<nblk, 256, 0, stream>>>(cnt, offs, bsums, N);
    scan_phase1<<<1, 256, 0, stream>>>(bsums, boffs, bdummy, nblk);
    scan_add<<<(N + 255) / 256, 256, 0, stream>>>(offs, boffs, N);
    fill_csr<<<(E + 255) / 256, 256, 0, stream>>>(src, dst, offs, cursor, csr, E);

    // Layer 1: mean = agg(x); h = relu(mean@W1l + x@W1r + b1)
    aggregate_mean<<<(N + 3) / 4, 256, 0, stream>>>(x, offs, cnt, csr, mean, N);
    gemm_tile<8, true, true><<<(N + 127) / 128, 256, 0, stream>>>(mean, W1l, x, W1r, b1, h, N);

    // Layer 2: mean = agg(h); emb = mean@W2l + h@W2r + b2
    aggregate_mean<<<(N + 3) / 4, 256, 0, stream>>>(h, offs, cnt, csr, mean, N);
    gemm_tile<8, true, false><<<(N + 127) / 128, 256, 0, stream>>>(mean, W2l, h, W2r, b2, emb, N);

    // out = emb @ Wm + bm   (reads raw emb)
    gemm_tile<4, false, false><<<(N + 127) / 128, 256, 0, stream>>>(emb, Wm, nullptr, nullptr, bm, outp, N);

    // emb_n = emb / max(||emb||, 1e-12)  (in place)
    normalize_rows<<<(N + 3) / 4, 256, 0, stream>>>(emb, N);
}

// Round 3
// 558.843 us; speedup vs baseline: 1.3236x; 1.3236x over previous
//
#include <hip/hip_runtime.h>
#include <hip/hip_fp16.h>
#include <cstdint>
#include <cstddef>

#define N_NODES 100000
#define N_EDGES 1600000

// ---------------- fp16 helpers ----------------

__device__ __forceinline__ float h2f(ushort u) {
    __half_raw r;
    r.x = u;
    return __half2float(__half(r));
}

__device__ __forceinline__ ushort f2h(float f) {
    __half h = __float2half(f);
    return static_cast<__half_raw>(h).x;
}

// ---------------- CSR build ----------------

__global__ void count_edges(const int* __restrict__ dst, int* __restrict__ cnt, int E) {
    int e = blockIdx.x * blockDim.x + threadIdx.x;
    if (e < E) atomicAdd(&cnt[dst[e]], 1);
}

__global__ void scan_phase1(const int* __restrict__ in, int* __restrict__ out,
                            int* __restrict__ blockSums, int n) {
    __shared__ int sdata[256];
    int base = blockIdx.x * 1024 + threadIdx.x * 4;
    int v0 = 0, v1 = 0, v2 = 0, v3 = 0;
    if (base + 0 < n) v0 = in[base + 0];
    if (base + 1 < n) v1 = in[base + 1];
    if (base + 2 < n) v2 = in[base + 2];
    if (base + 3 < n) v3 = in[base + 3];
    int s = v0 + v1 + v2 + v3;
    sdata[threadIdx.x] = s;
    __syncthreads();
    int acc = s;
    for (int off = 1; off < 256; off <<= 1) {
        int t = (threadIdx.x >= off) ? sdata[threadIdx.x - off] : 0;
        __syncthreads();
        acc += t;
        sdata[threadIdx.x] = acc;
        __syncthreads();
    }
    int excl = acc - s;
    if (base + 0 < n) out[base + 0] = excl;
    if (base + 1 < n) out[base + 1] = excl + v0;
    if (base + 2 < n) out[base + 2] = excl + v0 + v1;
    if (base + 3 < n) out[base + 3] = excl + v0 + v1 + v2;
    if (threadIdx.x == 255 && blockSums) blockSums[blockIdx.x] = acc;
}

__global__ void scan_add(int* __restrict__ offs, const int* __restrict__ blockOffs, int n) {
    int i = blockIdx.x * blockDim.x + threadIdx.x;
    if (i < n) offs[i] += blockOffs[i >> 10];
}

__global__ void fill_csr(const int* __restrict__ src, const int* __restrict__ dst,
                         const int* __restrict__ offs, int* __restrict__ cursor,
                         int* __restrict__ csr, int E) {
    int e = blockIdx.x * blockDim.x + threadIdx.x;
    if (e < E) {
        int d = dst[e];
        int p = atomicAdd(&cursor[d], 1);
        csr[offs[d] + p] = src[e];
    }
}

// ---------------- cast fp32 -> fp16 table ----------------

__global__ void cast_f32_f16(const float* __restrict__ in, ushort* __restrict__ out, int n4) {
    int i = blockIdx.x * blockDim.x + threadIdx.x;
    if (i < n4) {
        float4 v = reinterpret_cast<const float4*>(in)[i];
        ushort4 o;
        o.x = f2h(v.x);
        o.y = f2h(v.y);
        o.z = f2h(v.z);
        o.w = f2h(v.w);
        reinterpret_cast<ushort4*>(out)[i] = o;
    }
}

// ---------------- mean aggregation: one wave per node, fp16 gather ----------------
// 4 edges in flight per wave-iteration: lanes split into 4 groups of 16;
// group g handles edge j+g, each lane loads 8 halves (16 B) of that row.
// All groups cover the same 128 channels -> cross-group shfl_xor reduce.

__global__ void aggregate_mean_f16(const ushort* __restrict__ F, const int* __restrict__ offs,
                                   const int* __restrict__ cnt, const int* __restrict__ csr,
                                   float* __restrict__ out, int n) {
    int w = (blockIdx.x * blockDim.x + threadIdx.x) >> 6;
    int lane = threadIdx.x & 63;
    if (w >= n) return;
    int g = lane >> 4;   // edge group 0..3
    int cl = lane & 15;  // channel slot: channels cl*8 .. cl*8+7
    int beg = offs[w];
    int c = cnt[w];
    float a0 = 0.f, a1 = 0.f, a2 = 0.f, a3 = 0.f;
    float a4 = 0.f, a5 = 0.f, a6 = 0.f, a7 = 0.f;
    for (int j0 = 0; j0 < c; j0 += 64) {
        int m = c - j0;
        if (m > 64) m = 64;
        int myidx = (lane < m) ? csr[beg + j0 + lane] : 0;
#pragma unroll 2
        for (int j = 0; j < m; j += 4) {
            int e = j + g;
            int ee = (e < m) ? e : 0;
            int s = __shfl(myidx, ee);
            if (e < m) {
                uint4 v = *reinterpret_cast<const uint4*>(F + (size_t)s * 128 + cl * 8);
                a0 += h2f((ushort)(v.x & 0xffff));
                a1 += h2f((ushort)(v.x >> 16));
                a2 += h2f((ushort)(v.y & 0xffff));
                a3 += h2f((ushort)(v.y >> 16));
                a4 += h2f((ushort)(v.z & 0xffff));
                a5 += h2f((ushort)(v.z >> 16));
                a6 += h2f((ushort)(v.w & 0xffff));
                a7 += h2f((ushort)(v.w >> 16));
            }
        }
    }
    // reduce across the 4 groups (lanes xor 16, xor 32)
    a0 += __shfl_xor(a0, 16); a1 += __shfl_xor(a1, 16);
    a2 += __shfl_xor(a2, 16); a3 += __shfl_xor(a3, 16);
    a4 += __shfl_xor(a4, 16); a5 += __shfl_xor(a5, 16);
    a6 += __shfl_xor(a6, 16); a7 += __shfl_xor(a7, 16);
    a0 += __shfl_xor(a0, 32); a1 += __shfl_xor(a1, 32);
    a2 += __shfl_xor(a2, 32); a3 += __shfl_xor(a3, 32);
    a4 += __shfl_xor(a4, 32); a5 += __shfl_xor(a5, 32);
    a6 += __shfl_xor(a6, 32); a7 += __shfl_xor(a7, 32);
    if (g == 0) {
        float inv = 1.0f / fmaxf((float)c, 1.0f);
        float4 r0, r1;
        r0.x = a0 * inv; r0.y = a1 * inv; r0.z = a2 * inv; r0.w = a3 * inv;
        r1.x = a4 * inv; r1.y = a5 * inv; r1.z = a6 * inv; r1.w = a7 * inv;
        *reinterpret_cast<float4*>(out + (size_t)w * 128 + cl * 8) = r0;
        *reinterpret_cast<float4*>(out + (size_t)w * 128 + cl * 8 + 4) = r1;
    }
}

// ---------------- fused fp32 tiled GEMM ----------------
// C[r][c] = A1[r][:]@W1[:][c] (+ A2[r][:]@W2[:][c]) + bias[c]  (+relu)
// Optional fp16 shadow copy of C written to Ch (for next layer's gather).

template <int TN, bool HAS_A2, bool RELU>
__global__ __launch_bounds__(256) void gemm_tile(const float* __restrict__ A1,
                                                 const float* __restrict__ W1,
                                                 const float* __restrict__ A2,
                                                 const float* __restrict__ W2,
                                                 const float* __restrict__ bias,
                                                 float* __restrict__ C,
                                                 ushort* __restrict__ Ch, int n) {
    constexpr int BN = TN * 16;
    constexpr int TM = 8;
    __shared__ float As[8 * 128];   // As[kk][r]  (transposed)
    __shared__ float Bs[8 * BN];    // Bs[kk][c]
    int tid = threadIdx.x;
    int tx = tid & 15, ty = tid >> 4;
    int r0 = ty * TM, c0 = tx * TN;
    int row0 = blockIdx.x * 128;

    float acc[TM][TN];
#pragma unroll
    for (int i = 0; i < TM; i++)
#pragma unroll
        for (int j = 0; j < TN; j++) acc[i][j] = 0.f;

    const float* Ap[2] = {A1, A2};
    const float* Wp[2] = {W1, W2};
    const int nseg = HAS_A2 ? 2 : 1;

    for (int seg = 0; seg < nseg; ++seg) {
        const float* A = Ap[seg];
        const float* W = Wp[seg];
        for (int k0 = 0; k0 < 128; k0 += 8) {
            __syncthreads();
            {
                int r = tid >> 1;
                int kg = (tid & 1) * 4;
                int grow = row0 + r;
                float4 v = make_float4(0.f, 0.f, 0.f, 0.f);
                if (grow < n)
                    v = *reinterpret_cast<const float4*>(A + (size_t)grow * 128 + k0 + kg);
                As[(kg + 0) * 128 + r] = v.x;
                As[(kg + 1) * 128 + r] = v.y;
                As[(kg + 2) * 128 + r] = v.z;
                As[(kg + 3) * 128 + r] = v.w;
            }
            if constexpr (BN == 128) {
                int kk = tid >> 5;
                int c = (tid & 31) * 4;
                *reinterpret_cast<float4*>(&Bs[kk * BN + c]) =
                    *reinterpret_cast<const float4*>(W + (size_t)(k0 + kk) * BN + c);
            } else {
                int kk = tid >> 5;
                int c = (tid & 31) * 2;
                *reinterpret_cast<float2*>(&Bs[kk * BN + c]) =
                    *reinterpret_cast<const float2*>(W + (size_t)(k0 + kk) * BN + c);
            }
            __syncthreads();
#pragma unroll
            for (int kk = 0; kk < 8; ++kk) {
                float a[TM], b[TN];
#pragma unroll
                for (int i = 0; i < TM; i++) a[i] = As[kk * 128 + r0 + i];
#pragma unroll
                for (int j = 0; j < TN; j++) b[j] = Bs[kk * BN + c0 + j];
#pragma unroll
                for (int i = 0; i < TM; i++)
#pragma unroll
                    for (int j = 0; j < TN; j++) acc[i][j] += a[i] * b[j];
            }
        }
    }

    float bv[TN];
#pragma unroll
    for (int j = 0; j < TN; j++) bv[j] = bias ? bias[c0 + j] : 0.f;
#pragma unroll
    for (int i = 0; i < TM; i++) {
        int grow = row0 + r0 + i;
        if (grow < n) {
            float vrow[TN];
#pragma unroll
            for (int j = 0; j < TN; j++) {
                float v = acc[i][j] + bv[j];
                if (RELU) v = fmaxf(v, 0.f);
                vrow[j] = v;
                C[(size_t)grow * BN + c0 + j] = v;
            }
            if (Ch) {
#pragma unroll
                for (int j = 0; j < TN; j += 4) {
                    ushort4 o;
                    o.x = f2h(vrow[j + 0]);
                    o.y = f2h(vrow[j + 1]);
                    o.z = f2h(vrow[j + 2]);
                    o.w = f2h(vrow[j + 3]);
                    *reinterpret_cast<ushort4*>(Ch + (size_t)grow * BN + c0 + j) = o;
                }
            }
        }
    }
}

// ---------------- in-place row L2 normalize ----------------

__global__ void normalize_rows(float* __restrict__ emb, int n) {
    int w = (blockIdx.x * blockDim.x + threadIdx.x) >> 6;
    int lane = threadIdx.x & 63;
    if (w >= n) return;
    float2 v = *reinterpret_cast<float2*>(emb + (size_t)w * 128 + lane * 2);
    float ss = v.x * v.x + v.y * v.y;
    for (int off = 1; off < 64; off <<= 1) ss += __shfl_xor(ss, off);
    float norm = sqrtf(ss);
    float inv = 1.0f / fmaxf(norm, 1e-12f);
    v.x *= inv;
    v.y *= inv;
    *reinterpret_cast<float2*>(emb + (size_t)w * 128 + lane * 2) = v;
}

// ---------------- launch ----------------

extern "C" void kernel_launch(void* const* d_in, const int* in_sizes, int n_in,
                              void* d_out, int out_size, void* d_ws, size_t ws_size,
                              hipStream_t stream) {
    const float* x   = (const float*)d_in[0];
    const int*   ei  = (const int*)d_in[1];
    const float* W1l = (const float*)d_in[2];
    const float* b1  = (const float*)d_in[3];
    const float* W1r = (const float*)d_in[4];
    const float* W2l = (const float*)d_in[5];
    const float* b2  = (const float*)d_in[6];
    const float* W2r = (const float*)d_in[7];
    const float* Wm  = (const float*)d_in[8];
    const float* bm  = (const float*)d_in[9];

    const int N = N_NODES, E = N_EDGES;
    const int* src = ei;
    const int* dst = ei + E;

    char* ws = (char*)d_ws;
    int* cnt    = (int*)ws;  ws += sizeof(int) * N;
    int* offs   = (int*)ws;  ws += sizeof(int) * N;
    int* cursor = (int*)ws;  ws += sizeof(int) * N;
    int* csr    = (int*)ws;  ws += sizeof(int) * E;
    int* bsums  = (int*)ws;  ws += sizeof(int) * 128;
    int* boffs  = (int*)ws;  ws += sizeof(int) * 128;
    int* bdummy = (int*)ws;  ws += sizeof(int) * 4;
    uintptr_t p = (uintptr_t)ws;
    p = (p + 255) & ~(uintptr_t)255;
    float* mean   = (float*)p;                       // N*128 f32
    float* h      = mean + (size_t)N * 128;          // N*128 f32
    ushort* x_f16 = (ushort*)(h + (size_t)N * 128);  // N*128 fp16
    ushort* h_f16 = x_f16 + (size_t)N * 128;         // N*128 fp16

    float* outp = (float*)d_out;            // N x 64
    float* emb  = outp + (size_t)N * 64;    // N x 128 (raw emb, normalized in place at end)

    hipMemsetAsync(cnt, 0, sizeof(int) * N, stream);
    hipMemsetAsync(cursor, 0, sizeof(int) * N, stream);
    count_edges<<<(E + 255) / 256, 256, 0, stream>>>(dst, cnt, E);
    int nblk = (N + 1023) / 1024;  // 98
    scan_phase1<<<nblk, 256, 0, stream>>>(cnt, offs, bsums, N);
    scan_phase1<<<1, 256, 0, stream>>>(bsums, boffs, bdummy, nblk);
    scan_add<<<(N + 255) / 256, 256, 0, stream>>>(offs, boffs, N);
    fill_csr<<<(E + 255) / 256, 256, 0, stream>>>(src, dst, offs, cursor, csr, E);

    // fp16 shadow of x for the gather
    int n4 = N * 128 / 4;
    cast_f32_f16<<<(n4 + 255) / 256, 256, 0, stream>>>(x, x_f16, n4);

    // Layer 1: mean = agg(x_f16); h = relu(mean@W1l + x@W1r + b1)   (+ h_f16 shadow)
    aggregate_mean_f16<<<(N + 3) / 4, 256, 0, stream>>>(x_f16, offs, cnt, csr, mean, N);
    gemm_tile<8, true, true><<<(N + 127) / 128, 256, 0, stream>>>(mean, W1l, x, W1r, b1, h, h_f16, N);

    // Layer 2: mean = agg(h_f16); emb = mean@W2l + h@W2r + b2
    aggregate_mean_f16<<<(N + 3) / 4, 256, 0, stream>>>(h_f16, offs, cnt, csr, mean, N);
    gemm_tile<8, true, false><<<(N + 127) / 128, 256, 0, stream>>>(mean, W2l, h, W2r, b2, emb, nullptr, N);

    // out = emb @ Wm + bm
    gemm_tile<4, false, false><<<(N + 127) / 128, 256, 0, stream>>>(emb, Wm, nullptr, nullptr, bm, outp, nullptr, N);

    // emb_n = emb / max(||emb||, 1e-12)  (in place)
    normalize_rows<<<(N + 3) / 4, 256, 0, stream>>>(emb, N);
}

// Round 4
// 428.909 us; speedup vs baseline: 1.7246x; 1.3029x over previous
//
#include <hip/hip_runtime.h>
#include <hip/hip_fp16.h>
#include <cstdint>
#include <cstddef>

#define N_NODES 100000
#define N_EDGES 1600000

typedef _Float16 f16x8 __attribute__((ext_vector_type(8)));
typedef float f32x4 __attribute__((ext_vector_type(4)));

// ---------------- fp16 helpers ----------------

__device__ __forceinline__ float h2f(ushort u) {
    __half_raw r;
    r.x = u;
    return __half2float(__half(r));
}

__device__ __forceinline__ ushort f2h(float f) {
    __half h = __float2half(f);
    return static_cast<__half_raw>(h).x;
}

// ---------------- CSR build ----------------

__global__ void count_edges(const int* __restrict__ dst, int* __restrict__ cnt, int E) {
    int e = blockIdx.x * blockDim.x + threadIdx.x;
    if (e < E) atomicAdd(&cnt[dst[e]], 1);
}

__global__ void scan_phase1(const int* __restrict__ in, int* __restrict__ out,
                            int* __restrict__ blockSums, int n) {
    __shared__ int sdata[256];
    int base = blockIdx.x * 1024 + threadIdx.x * 4;
    int v0 = 0, v1 = 0, v2 = 0, v3 = 0;
    if (base + 0 < n) v0 = in[base + 0];
    if (base + 1 < n) v1 = in[base + 1];
    if (base + 2 < n) v2 = in[base + 2];
    if (base + 3 < n) v3 = in[base + 3];
    int s = v0 + v1 + v2 + v3;
    sdata[threadIdx.x] = s;
    __syncthreads();
    int acc = s;
    for (int off = 1; off < 256; off <<= 1) {
        int t = (threadIdx.x >= off) ? sdata[threadIdx.x - off] : 0;
        __syncthreads();
        acc += t;
        sdata[threadIdx.x] = acc;
        __syncthreads();
    }
    int excl = acc - s;
    if (base + 0 < n) out[base + 0] = excl;
    if (base + 1 < n) out[base + 1] = excl + v0;
    if (base + 2 < n) out[base + 2] = excl + v0 + v1;
    if (base + 3 < n) out[base + 3] = excl + v0 + v1 + v2;
    if (threadIdx.x == 255 && blockSums) blockSums[blockIdx.x] = acc;
}

__global__ void scan_add(int* __restrict__ offs, const int* __restrict__ blockOffs, int n) {
    int i = blockIdx.x * blockDim.x + threadIdx.x;
    if (i < n) offs[i] += blockOffs[i >> 10];
}

__global__ void fill_csr(const int* __restrict__ src, const int* __restrict__ dst,
                         const int* __restrict__ offs, int* __restrict__ cursor,
                         int* __restrict__ csr, int E) {
    int e = blockIdx.x * blockDim.x + threadIdx.x;
    if (e < E) {
        int d = dst[e];
        int p = atomicAdd(&cursor[d], 1);
        csr[offs[d] + p] = src[e];
    }
}

// ---------------- cast fp32 -> fp16 table ----------------

__global__ void cast_f32_f16(const float* __restrict__ in, ushort* __restrict__ out, int n4) {
    int i = blockIdx.x * blockDim.x + threadIdx.x;
    if (i < n4) {
        float4 v = reinterpret_cast<const float4*>(in)[i];
        ushort4 o;
        o.x = f2h(v.x);
        o.y = f2h(v.y);
        o.z = f2h(v.z);
        o.w = f2h(v.w);
        reinterpret_cast<ushort4*>(out)[i] = o;
    }
}

// ---------------- transpose-cast weights: W[K][C] f32 -> WT[C][K] f16 ----------------

__global__ void transpose_cast(const float* __restrict__ W, ushort* __restrict__ WT,
                               int K, int C) {
    int idx = blockIdx.x * blockDim.x + threadIdx.x;
    if (idx < K * C) {
        int k = idx / C, c = idx % C;  // coalesced read along C
        WT[(size_t)c * K + k] = f2h(W[idx]);
    }
}

// ---------------- mean aggregation: one wave per node, fp16 gather, fp16 out ----------------

__global__ void aggregate_mean_f16(const ushort* __restrict__ F, const int* __restrict__ offs,
                                   const int* __restrict__ cnt, const int* __restrict__ csr,
                                   ushort* __restrict__ out, int n) {
    int w = (blockIdx.x * blockDim.x + threadIdx.x) >> 6;
    int lane = threadIdx.x & 63;
    if (w >= n) return;
    int g = lane >> 4;   // edge group 0..3
    int cl = lane & 15;  // channel slot: channels cl*8 .. cl*8+7
    int beg = offs[w];
    int c = cnt[w];
    float a0 = 0.f, a1 = 0.f, a2 = 0.f, a3 = 0.f;
    float a4 = 0.f, a5 = 0.f, a6 = 0.f, a7 = 0.f;
    for (int j0 = 0; j0 < c; j0 += 64) {
        int m = c - j0;
        if (m > 64) m = 64;
        int myidx = (lane < m) ? csr[beg + j0 + lane] : 0;
#pragma unroll 2
        for (int j = 0; j < m; j += 4) {
            int e = j + g;
            int ee = (e < m) ? e : 0;
            int s = __shfl(myidx, ee);
            if (e < m) {
                uint4 v = *reinterpret_cast<const uint4*>(F + (size_t)s * 128 + cl * 8);
                a0 += h2f((ushort)(v.x & 0xffff));
                a1 += h2f((ushort)(v.x >> 16));
                a2 += h2f((ushort)(v.y & 0xffff));
                a3 += h2f((ushort)(v.y >> 16));
                a4 += h2f((ushort)(v.z & 0xffff));
                a5 += h2f((ushort)(v.z >> 16));
                a6 += h2f((ushort)(v.w & 0xffff));
                a7 += h2f((ushort)(v.w >> 16));
            }
        }
    }
    a0 += __shfl_xor(a0, 16); a1 += __shfl_xor(a1, 16);
    a2 += __shfl_xor(a2, 16); a3 += __shfl_xor(a3, 16);
    a4 += __shfl_xor(a4, 16); a5 += __shfl_xor(a5, 16);
    a6 += __shfl_xor(a6, 16); a7 += __shfl_xor(a7, 16);
    a0 += __shfl_xor(a0, 32); a1 += __shfl_xor(a1, 32);
    a2 += __shfl_xor(a2, 32); a3 += __shfl_xor(a3, 32);
    a4 += __shfl_xor(a4, 32); a5 += __shfl_xor(a5, 32);
    a6 += __shfl_xor(a6, 32); a7 += __shfl_xor(a7, 32);
    if (g == 0) {
        float inv = 1.0f / fmaxf((float)c, 1.0f);
        uint4 o;
        o.x = (uint)f2h(a0 * inv) | ((uint)f2h(a1 * inv) << 16);
        o.y = (uint)f2h(a2 * inv) | ((uint)f2h(a3 * inv) << 16);
        o.z = (uint)f2h(a4 * inv) | ((uint)f2h(a5 * inv) << 16);
        o.w = (uint)f2h(a6 * inv) | ((uint)f2h(a7 * inv) << 16);
        *reinterpret_cast<uint4*>(out + (size_t)w * 128 + cl * 8) = o;
    }
}

// ---------------- MFMA fp16 GEMM, fp32 accumulate ----------------
// C[r][c] = A1[r][:]@B1[:][c] (+ A2[r][:]@B2[:][c]) + bias[c]  (+relu)
// A: fp16 row-major [n][128]. B passed TRANSPOSED fp16: BT[c][k], c<N, k<128.
// Block = 256 threads = 4 waves; block covers 128 rows x N cols; wave covers 32 rows.
// Fragment layout (mfma_f32_16x16x32_f16): A/B: idx=lane&15 (row/col),
// k=(lane>>4)*8 + j; D: col=lane&15, row=(lane>>4)*4 + reg.

template <int NFRAG, bool HAS_A2, bool RELU, bool WF32, bool WF16>
__global__ __launch_bounds__(256) void mfma_gemm(const ushort* __restrict__ A1,
                                                 const ushort* __restrict__ B1T,
                                                 const ushort* __restrict__ A2,
                                                 const ushort* __restrict__ B2T,
                                                 const float* __restrict__ bias,
                                                 float* __restrict__ Cf,
                                                 ushort* __restrict__ Ch, int n) {
    constexpr int NC = NFRAG * 16;
    int wid = threadIdx.x >> 6;
    int lane = threadIdx.x & 63;
    int row0 = blockIdx.x * 128 + wid * 32;
    int fr = lane & 15;          // A-row / B-col within fragment
    int ko = (lane >> 4) * 8;    // k offset within 32-wide k step

    f32x4 acc[2][NFRAG];
#pragma unroll
    for (int m = 0; m < 2; m++)
#pragma unroll
        for (int nf = 0; nf < NFRAG; nf++) acc[m][nf] = (f32x4)0.f;

    const int nseg = HAS_A2 ? 2 : 1;
    for (int seg = 0; seg < nseg; ++seg) {
        const ushort* A = seg ? A2 : A1;
        const ushort* BT = seg ? B2T : B1T;
#pragma unroll
        for (int k0 = 0; k0 < 128; k0 += 32) {
            f16x8 av[2];
#pragma unroll
            for (int m = 0; m < 2; m++) {
                int row = row0 + m * 16 + fr;
                if (row >= n) row = n - 1;  // stores are guarded; keep loads in-range
                av[m] = *reinterpret_cast<const f16x8*>(A + (size_t)row * 128 + k0 + ko);
            }
            f16x8 bv[NFRAG];
#pragma unroll
            for (int nf = 0; nf < NFRAG; nf++)
                bv[nf] = *reinterpret_cast<const f16x8*>(BT + (size_t)(nf * 16 + fr) * 128 + k0 + ko);
#pragma unroll
            for (int m = 0; m < 2; m++)
#pragma unroll
                for (int nf = 0; nf < NFRAG; nf++)
                    acc[m][nf] = __builtin_amdgcn_mfma_f32_16x16x32_f16(av[m], bv[nf], acc[m][nf], 0, 0, 0);
        }
    }

    int crow = (lane >> 4) * 4;
    int ccol = lane & 15;
    float bv[NFRAG];
#pragma unroll
    for (int nf = 0; nf < NFRAG; nf++) bv[nf] = bias[nf * 16 + ccol];

#pragma unroll
    for (int m = 0; m < 2; m++) {
#pragma unroll
        for (int reg = 0; reg < 4; reg++) {
            int grow = row0 + m * 16 + crow + reg;
            if (grow < n) {
#pragma unroll
                for (int nf = 0; nf < NFRAG; nf++) {
                    float v = acc[m][nf][reg] + bv[nf];
                    if (RELU) v = fmaxf(v, 0.f);
                    if (WF32) Cf[(size_t)grow * NC + nf * 16 + ccol] = v;
                    if (WF16) Ch[(size_t)grow * NC + nf * 16 + ccol] = f2h(v);
                }
            }
        }
    }
}

// ---------------- in-place row L2 normalize ----------------

__global__ void normalize_rows(float* __restrict__ emb, int n) {
    int w = (blockIdx.x * blockDim.x + threadIdx.x) >> 6;
    int lane = threadIdx.x & 63;
    if (w >= n) return;
    float2 v = *reinterpret_cast<float2*>(emb + (size_t)w * 128 + lane * 2);
    float ss = v.x * v.x + v.y * v.y;
    for (int off = 1; off < 64; off <<= 1) ss += __shfl_xor(ss, off);
    float norm = sqrtf(ss);
    float inv = 1.0f / fmaxf(norm, 1e-12f);
    v.x *= inv;
    v.y *= inv;
    *reinterpret_cast<float2*>(emb + (size_t)w * 128 + lane * 2) = v;
}

// ---------------- launch ----------------

extern "C" void kernel_launch(void* const* d_in, const int* in_sizes, int n_in,
                              void* d_out, int out_size, void* d_ws, size_t ws_size,
                              hipStream_t stream) {
    const float* x   = (const float*)d_in[0];
    const int*   ei  = (const int*)d_in[1];
    const float* W1l = (const float*)d_in[2];
    const float* b1  = (const float*)d_in[3];
    const float* W1r = (const float*)d_in[4];
    const float* W2l = (const float*)d_in[5];
    const float* b2  = (const float*)d_in[6];
    const float* W2r = (const float*)d_in[7];
    const float* Wm  = (const float*)d_in[8];
    const float* bm  = (const float*)d_in[9];

    const int N = N_NODES, E = N_EDGES;
    const int* src = ei;
    const int* dst = ei + E;

    char* ws = (char*)d_ws;
    int* cnt    = (int*)ws;  ws += sizeof(int) * N;
    int* offs   = (int*)ws;  ws += sizeof(int) * N;
    int* cursor = (int*)ws;  ws += sizeof(int) * N;
    int* csr    = (int*)ws;  ws += sizeof(int) * E;
    int* bsums  = (int*)ws;  ws += sizeof(int) * 128;
    int* boffs  = (int*)ws;  ws += sizeof(int) * 128;
    int* bdummy = (int*)ws;  ws += sizeof(int) * 4;
    uintptr_t p = (uintptr_t)ws;
    p = (p + 255) & ~(uintptr_t)255;
    ushort* mean_f16 = (ushort*)p;                      // N*128 fp16
    ushort* x_f16    = mean_f16 + (size_t)N * 128;
    ushort* h_f16    = x_f16 + (size_t)N * 128;
    ushort* emb_f16  = h_f16 + (size_t)N * 128;
    ushort* W1lT     = emb_f16 + (size_t)N * 128;       // [128][128] fp16
    ushort* W1rT     = W1lT + 128 * 128;
    ushort* W2lT     = W1rT + 128 * 128;
    ushort* W2rT     = W2lT + 128 * 128;
    ushort* WmT      = W2rT + 128 * 128;                // [64][128] fp16

    float* outp = (float*)d_out;            // N x 64
    float* emb  = outp + (size_t)N * 64;    // N x 128 (raw emb, normalized in place at end)

    hipMemsetAsync(cnt, 0, sizeof(int) * N, stream);
    hipMemsetAsync(cursor, 0, sizeof(int) * N, stream);
    count_edges<<<(E + 255) / 256, 256, 0, stream>>>(dst, cnt, E);
    int nblk = (N + 1023) / 1024;  // 98
    scan_phase1<<<nblk, 256, 0, stream>>>(cnt, offs, bsums, N);
    scan_phase1<<<1, 256, 0, stream>>>(bsums, boffs, bdummy, nblk);
    scan_add<<<(N + 255) / 256, 256, 0, stream>>>(offs, boffs, N);
    fill_csr<<<(E + 255) / 256, 256, 0, stream>>>(src, dst, offs, cursor, csr, E);

    // fp16 shadow of x; fp16 transposed weights
    int n4 = N * 128 / 4;
    cast_f32_f16<<<(n4 + 255) / 256, 256, 0, stream>>>(x, x_f16, n4);
    transpose_cast<<<(128 * 128 + 255) / 256, 256, 0, stream>>>(W1l, W1lT, 128, 128);
    transpose_cast<<<(128 * 128 + 255) / 256, 256, 0, stream>>>(W1r, W1rT, 128, 128);
    transpose_cast<<<(128 * 128 + 255) / 256, 256, 0, stream>>>(W2l, W2lT, 128, 128);
    transpose_cast<<<(128 * 128 + 255) / 256, 256, 0, stream>>>(W2r, W2rT, 128, 128);
    transpose_cast<<<(128 * 64 + 255) / 256, 256, 0, stream>>>(Wm, WmT, 128, 64);

    int gblk = (N + 127) / 128;  // 782

    // Layer 1: mean = agg(x_f16); h_f16 = relu(mean@W1l + x@W1r + b1)
    aggregate_mean_f16<<<(N + 3) / 4, 256, 0, stream>>>(x_f16, offs, cnt, csr, mean_f16, N);
    mfma_gemm<8, true, true, false, true><<<gblk, 256, 0, stream>>>(
        mean_f16, W1lT, x_f16, W1rT, b1, nullptr, h_f16, N);

    // Layer 2: mean = agg(h_f16); emb = mean@W2l + h@W2r + b2  (fp32 + fp16 shadow)
    aggregate_mean_f16<<<(N + 3) / 4, 256, 0, stream>>>(h_f16, offs, cnt, csr, mean_f16, N);
    mfma_gemm<8, true, false, true, true><<<gblk, 256, 0, stream>>>(
        mean_f16, W2lT, h_f16, W2rT, b2, emb, emb_f16, N);

    // out = emb @ Wm + bm
    mfma_gemm<4, false, false, true, false><<<gblk, 256, 0, stream>>>(
        emb_f16, WmT, nullptr, nullptr, bm, outp, nullptr, N);

    // emb_n = emb / max(||emb||, 1e-12)  (in place)
    normalize_rows<<<(N + 3) / 4, 256, 0, stream>>>(emb, N);
}